// Round 1
// baseline (264.976 us; speedup 1.0000x reference)
//
#include <hip/hip_runtime.h>

#define NEDGE 20000
#define ECH   128
#define RAD   1920
#define OPE   9600   // output floats per edge (5*3*2*320)
#define BE    16     // edges per block

typedef short bf16x8 __attribute__((ext_vector_type(8)));
typedef float f32x4  __attribute__((ext_vector_type(4)));

__device__ __forceinline__ unsigned short f2bf(float f) {
  unsigned u = __float_as_uint(f);
  u += 0x7fffu + ((u >> 16) & 1u);
  return (unsigned short)(u >> 16);
}

// ---------------- prep: transposed bf16 weights into ws ----------------
// ws layout (ushort):
//   [0,16384)                w1t[128 n][128 k]  = w1[k][n]
//   [16384, 16384+245760)    w2t[1920 n][128 k] = w2[k][n]
//   [262144, 262144+245760)  wt[m][R][320 o][128 rc] combined complex weight
__global__ __launch_bounds__(256) void prep_kernel(
    const float* __restrict__ w1, const float* __restrict__ w2,
    const float* __restrict__ Wr, const float* __restrict__ Wi,
    unsigned short* __restrict__ ws) {
  int gid = blockIdx.x * 256 + threadIdx.x;
  unsigned short* w1t = ws;
  unsigned short* w2t = ws + 16384;
  unsigned short* wt  = ws + 16384 + 245760;
  if (gid < 16384) {
    int k = gid >> 7, n = gid & 127;
    w1t[n * 128 + k] = f2bf(w1[gid]);
  } else if (gid < 16384 + 245760) {
    int i = gid - 16384;
    int k = i / 1920, n = i - k * 1920;
    w2t[n * 128 + k] = f2bf(w2[i]);
  } else if (gid < 16384 + 245760 + 61440) {
    int i = gid - (16384 + 245760);      // i = (m*64+c)*320 + o
    int o = i % 320, mc = i / 320;
    int c = mc & 63, m = mc >> 6;
    float vr = Wr[i], vi = Wi[i];
    size_t b0 = ((size_t)((m * 2 + 0) * 320 + o)) * 128;
    size_t b1 = ((size_t)((m * 2 + 1) * 320 + o)) * 128;
    wt[b0 + c]      = f2bf(vr);    // R=0, r=0:  W_r
    wt[b0 + 64 + c] = f2bf(-vi);   // R=0, r=1: -W_i
    wt[b1 + c]      = f2bf(vi);    // R=1, r=0:  W_i
    wt[b1 + 64 + c] = f2bf(vr);    // R=1, r=1:  W_r
  }
}

// ---------------- fused: MLP + modulation + SO2 einsum + masked write ----
__global__ __launch_bounds__(256) void fused_kernel(
    const float* __restrict__ x,  const float* __restrict__ xe,
    const float* __restrict__ b1, const float* __restrict__ lng,
    const float* __restrict__ lnb, const float* __restrict__ b2,
    const unsigned short* __restrict__ ws, float* __restrict__ out) {

  const unsigned short* w1t = ws;
  const unsigned short* w2t = ws + 16384;
  const unsigned short* wt  = ws + 16384 + 245760;

  __shared__ unsigned short xsb[BE][136];  // xe tile (bf16), then xs tiles
  __shared__ unsigned short hb[BE][136];   // h after LN+SiLU (bf16)
  __shared__ float hp[BE][132];            // pre-LN h (fp32)

  const int tid  = threadIdx.x;
  const int wave = tid >> 6, lane = tid & 63;
  const int lq = lane >> 4, lr = lane & 15;
  const int e0 = blockIdx.x * BE;

  // ---- load x_edge tile as bf16 into LDS ----
  for (int s = tid; s < BE * 32; s += 256) {
    int e = s >> 5, k4 = s & 31;
    float4 v = *((const float4*)(xe + (size_t)(e0 + e) * ECH) + k4);
    ushort4 u;
    u.x = f2bf(v.x); u.y = f2bf(v.y); u.z = f2bf(v.z); u.w = f2bf(v.w);
    *(ushort4*)&xsb[e][k4 * 4] = u;
  }
  __syncthreads();

  // ---- GEMM1: h_pre = xe @ w1 (+b1), wave w owns output cols [32w,32w+32) ----
  {
    const int n0 = wave * 32;
    f32x4 c0 = {0.f, 0.f, 0.f, 0.f}, c1 = {0.f, 0.f, 0.f, 0.f};
#pragma unroll
    for (int ks = 0; ks < 4; ++ks) {
      bf16x8 a  = *(const bf16x8*)&xsb[lr][lq * 8 + ks * 32];
      bf16x8 bA = *(const bf16x8*)(w1t + (size_t)(n0 + lr) * 128 + lq * 8 + ks * 32);
      bf16x8 bB = *(const bf16x8*)(w1t + (size_t)(n0 + 16 + lr) * 128 + lq * 8 + ks * 32);
      c0 = __builtin_amdgcn_mfma_f32_16x16x32_bf16(a, bA, c0, 0, 0, 0);
      c1 = __builtin_amdgcn_mfma_f32_16x16x32_bf16(a, bB, c1, 0, 0, 0);
    }
    float bb0 = b1[n0 + lr], bb1 = b1[n0 + 16 + lr];
#pragma unroll
    for (int i = 0; i < 4; ++i) {
      int e = 4 * lq + i;
      hp[e][n0 + lr]      = c0[i] + bb0;
      hp[e][n0 + 16 + lr] = c1[i] + bb1;
    }
  }
  __syncthreads();

  // ---- LayerNorm + SiLU -> hb (bf16). 16 threads per edge, 8 ch each ----
  {
    int e = tid >> 4, j = tid & 15;
    float v[8];
    float4 a = *((const float4*)&hp[e][j * 8]);
    float4 b = *((const float4*)&hp[e][j * 8 + 4]);
    v[0] = a.x; v[1] = a.y; v[2] = a.z; v[3] = a.w;
    v[4] = b.x; v[5] = b.y; v[6] = b.z; v[7] = b.w;
    float s = 0.f, q = 0.f;
#pragma unroll
    for (int i = 0; i < 8; ++i) { s += v[i]; q += v[i] * v[i]; }
#pragma unroll
    for (int mk = 1; mk <= 8; mk <<= 1) {
      s += __shfl_xor(s, mk, 64);
      q += __shfl_xor(q, mk, 64);
    }
    float mean = s * (1.f / 128.f);
    float var  = q * (1.f / 128.f) - mean * mean;
    float rstd = rsqrtf(var + 1e-5f);
    float4 g0 = *((const float4*)&lng[j * 8]), g1 = *((const float4*)&lng[j * 8 + 4]);
    float4 t0 = *((const float4*)&lnb[j * 8]), t1 = *((const float4*)&lnb[j * 8 + 4]);
    float gg[8] = {g0.x, g0.y, g0.z, g0.w, g1.x, g1.y, g1.z, g1.w};
    float bb[8] = {t0.x, t0.y, t0.z, t0.w, t1.x, t1.y, t1.z, t1.w};
    ushort4 o0, o1;
    unsigned short uo[8];
#pragma unroll
    for (int i = 0; i < 8; ++i) {
      float hn = (v[i] - mean) * rstd * gg[i] + bb[i];
      float sv = hn / (1.f + __expf(-hn));
      uo[i] = f2bf(sv);
    }
    o0.x = uo[0]; o0.y = uo[1]; o0.z = uo[2]; o0.w = uo[3];
    o1.x = uo[4]; o1.y = uo[5]; o1.z = uo[6]; o1.w = uo[7];
    *(ushort4*)&hb[e][j * 8]     = o0;
    *(ushort4*)&hb[e][j * 8 + 4] = o1;
  }
  __syncthreads();

  // hoist A-fragments of h (same for every (l,m))
  bf16x8 hfr[4];
#pragma unroll
  for (int ks = 0; ks < 4; ++ks) hfr[ks] = *(const bf16x8*)&hb[lr][lq * 8 + ks * 32];

  static const signed char Lof[12] = {0, 1, 1, 2, 2, 2, 3, 3, 3, 4, 4, 4};
  static const signed char Mof[12] = {0, 0, 1, 0, 1, 2, 0, 1, 2, 0, 1, 2};

#pragma unroll 1
  for (int vi = 0; vi < 12; ++vi) {
    const int l = Lof[vi], m = Mof[vi], lm = l * 3 + m;

    // ---- GEMM2 chunk: rad[e, rc] for rc in [32w, 32w+32) ----
    const int n0 = wave * 32;
    f32x4 r0 = {0.f, 0.f, 0.f, 0.f}, r1 = {0.f, 0.f, 0.f, 0.f};
    const unsigned short* w2base = w2t + (size_t)(lm * 128) * 128;
#pragma unroll
    for (int ks = 0; ks < 4; ++ks) {
      bf16x8 b0 = *(const bf16x8*)(w2base + (size_t)(n0 + lr) * 128 + lq * 8 + ks * 32);
      bf16x8 b1v = *(const bf16x8*)(w2base + (size_t)(n0 + 16 + lr) * 128 + lq * 8 + ks * 32);
      r0 = __builtin_amdgcn_mfma_f32_16x16x32_bf16(hfr[ks], b0, r0, 0, 0, 0);
      r1 = __builtin_amdgcn_mfma_f32_16x16x32_bf16(hfr[ks], b1v, r1, 0, 0, 0);
    }
    // ---- xs = (rad + b2) * x  -> bf16 LDS ----
    float bb0 = b2[lm * 128 + n0 + lr], bb1 = b2[lm * 128 + n0 + 16 + lr];
#pragma unroll
    for (int i = 0; i < 4; ++i) {
      int e = 4 * lq + i;
      const float* xrow = x + (size_t)(e0 + e) * RAD + lm * 128;
      xsb[e][n0 + lr]      = f2bf((r0[i] + bb0) * xrow[n0 + lr]);
      xsb[e][n0 + 16 + lr] = f2bf((r1[i] + bb1) * xrow[n0 + 16 + lr]);
    }
    __syncthreads();

    // ---- einsum: out[e, R, o] = xs @ wt[m][R], masked N ----
    bf16x8 afr[4];
#pragma unroll
    for (int ks = 0; ks < 4; ++ks) afr[ks] = *(const bf16x8*)&xsb[lr][lq * 8 + ks * 32];

    const int totT = (lm == 0) ? 20 : ((m == 0) ? 4 : 8);
    for (int t = wave; t < totT; t += 4) {
      int R, o0v;
      if (lm == 0) { R = 0; o0v = t * 16; }
      else         { R = t >> 2; o0v = (t & 3) * 16; }
      const unsigned short* wb = wt + ((size_t)((m * 2 + R) * 320) + o0v) * 128;
      f32x4 acc = {0.f, 0.f, 0.f, 0.f};
#pragma unroll
      for (int ks = 0; ks < 4; ++ks) {
        bf16x8 b = *(const bf16x8*)(wb + (size_t)lr * 128 + lq * 8 + ks * 32);
        acc = __builtin_amdgcn_mfma_f32_16x16x32_bf16(afr[ks], b, acc, 0, 0, 0);
      }
      float* ob = out + (size_t)(e0 + 4 * lq) * OPE + lm * 640 + R * 320 + o0v + lr;
      ob[0 * OPE] = acc[0];
      ob[1 * OPE] = acc[1];
      ob[2 * OPE] = acc[2];
      ob[3 * OPE] = acc[3];
    }
    __syncthreads();
  }

  // ---- zero sweep: write the statically-known zero regions (float4) ----
  {
    static const int zr[22][3] = {  // {lm, start_f4, len_f4} within 160-f4 row
      {0, 80, 80},
      {1, 0, 160}, {2, 0, 160}, {5, 0, 160},
      {3, 16, 144}, {6, 16, 144}, {9, 16, 144}, {12, 16, 144},
      {4, 16, 64}, {4, 96, 64}, {7, 16, 64}, {7, 96, 64},
      {8, 16, 64}, {8, 96, 64}, {10, 16, 64}, {10, 96, 64},
      {11, 16, 64}, {11, 96, 64}, {13, 16, 64}, {13, 96, 64},
      {14, 16, 64}, {14, 96, 64}};
    const float4 z4 = make_float4(0.f, 0.f, 0.f, 0.f);
#pragma unroll
    for (int ri = 0; ri < 22; ++ri) {
      const int lm = zr[ri][0], s4 = zr[ri][1], n4 = zr[ri][2];
      for (int idx = tid; idx < n4 * BE; idx += 256) {
        int e = idx / n4, p = idx - e * n4;
        *((float4*)(out + (size_t)(e0 + e) * OPE + lm * 640) + (s4 + p)) = z4;
      }
    }
  }
}

extern "C" void kernel_launch(void* const* d_in, const int* in_sizes, int n_in,
                              void* d_out, int out_size, void* d_ws, size_t ws_size,
                              hipStream_t stream) {
  const float* x   = (const float*)d_in[0];
  const float* xe  = (const float*)d_in[1];
  const float* Wr  = (const float*)d_in[2];
  const float* Wi  = (const float*)d_in[3];
  const float* w1  = (const float*)d_in[4];
  const float* b1  = (const float*)d_in[5];
  const float* lng = (const float*)d_in[6];
  const float* lnb = (const float*)d_in[7];
  const float* w2  = (const float*)d_in[8];
  const float* b2  = (const float*)d_in[9];
  float* out = (float*)d_out;
  unsigned short* ws = (unsigned short*)d_ws;

  const int prepN = 16384 + 245760 + 61440;  // 323584 -> 1264 blocks exactly
  prep_kernel<<<(prepN + 255) / 256, 256, 0, stream>>>(w1, w2, Wr, Wi, ws);
  fused_kernel<<<NEDGE / BE, 256, 0, stream>>>(x, xe, b1, lng, lnb, b2, ws, out);
}

// Round 2
// 264.290 us; speedup vs baseline: 1.0026x; 1.0026x over previous
//
#include <hip/hip_runtime.h>

#define NEDGE 20000
#define ECH   128
#define RAD   1920
#define OPE   9600   // output floats per edge (5*3*2*320)
#define BE    16     // edges per block

typedef short bf16x8 __attribute__((ext_vector_type(8)));
typedef float f32x4  __attribute__((ext_vector_type(4)));

__device__ __forceinline__ unsigned short f2bf(float f) {
  unsigned u = __float_as_uint(f);
  u += 0x7fffu + ((u >> 16) & 1u);
  return (unsigned short)(u >> 16);
}

// ---------------- prep: transposed bf16 weights into ws ----------------
// ws layout (ushort):
//   [0,16384)                w1t[128 n][128 k]  = w1[k][n]
//   [16384, 16384+245760)    w2t[1920 n][128 k] = w2[k][n]
//   [262144, 262144+245760)  wt[m][R][320 o][128 rc] combined complex weight
__global__ __launch_bounds__(256) void prep_kernel(
    const float* __restrict__ w1, const float* __restrict__ w2,
    const float* __restrict__ Wr, const float* __restrict__ Wi,
    unsigned short* __restrict__ ws) {
  int gid = blockIdx.x * 256 + threadIdx.x;
  unsigned short* w1t = ws;
  unsigned short* w2t = ws + 16384;
  unsigned short* wt  = ws + 16384 + 245760;
  if (gid < 16384) {
    int k = gid >> 7, n = gid & 127;
    w1t[n * 128 + k] = f2bf(w1[gid]);
  } else if (gid < 16384 + 245760) {
    int i = gid - 16384;
    int k = i / 1920, n = i - k * 1920;
    w2t[n * 128 + k] = f2bf(w2[i]);
  } else if (gid < 16384 + 245760 + 61440) {
    int i = gid - (16384 + 245760);      // i = (m*64+c)*320 + o
    int o = i % 320, mc = i / 320;
    int c = mc & 63, m = mc >> 6;
    float vr = Wr[i], vi = Wi[i];
    size_t b0 = ((size_t)((m * 2 + 0) * 320 + o)) * 128;
    size_t b1 = ((size_t)((m * 2 + 1) * 320 + o)) * 128;
    wt[b0 + c]      = f2bf(vr);    // R=0, r=0:  W_r
    wt[b0 + 64 + c] = f2bf(-vi);   // R=0, r=1: -W_i
    wt[b1 + c]      = f2bf(vi);    // R=1, r=0:  W_i
    wt[b1 + 64 + c] = f2bf(vr);    // R=1, r=1:  W_r
  }
}

// balanced zero writer: N4 is a compile-time divisor
template<int N4>
__device__ __forceinline__ void zwrite(float* __restrict__ outb, int tid, int s4) {
  const float4 z4 = make_float4(0.f, 0.f, 0.f, 0.f);
  for (int p = tid; p < N4 * BE; p += 256) {
    int e = p / N4, f = p - e * N4;
    *((float4*)(outb + (size_t)e * OPE) + (s4 + f)) = z4;
  }
}

// ---------------- fused: MLP + modulation + SO2 einsum + masked write ----
// grid.x = 3750: eb = bid/3 owns edges [eb*16, eb*16+16); slab = bid%3 owns
// 4 of the 12 valid (l,m) plus a share of the zero regions.
__global__ __launch_bounds__(256, 4) void fused_kernel(
    const float* __restrict__ x,  const float* __restrict__ xe,
    const float* __restrict__ b1, const float* __restrict__ lng,
    const float* __restrict__ lnb, const float* __restrict__ b2,
    const unsigned short* __restrict__ ws, float* __restrict__ out) {

  const unsigned short* w1t = ws;
  const unsigned short* w2t = ws + 16384;
  const unsigned short* wt  = ws + 16384 + 245760;

  __shared__ unsigned short xsb[BE][136];  // xe tile (bf16), then xs tiles
  __shared__ unsigned short hb[BE][136];   // h after LN+SiLU (bf16)
  __shared__ float hp[BE][132];            // pre-LN h (fp32)

  const int tid  = threadIdx.x;
  const int wave = tid >> 6, lane = tid & 63;
  const int lq = lane >> 4, lr = lane & 15;
  const int eb = blockIdx.x / 3, slab = blockIdx.x % 3;
  const int e0 = eb * BE;

  // ---- load x_edge tile as bf16 into LDS ----
  for (int s = tid; s < BE * 32; s += 256) {
    int e = s >> 5, k4 = s & 31;
    float4 v = *((const float4*)(xe + (size_t)(e0 + e) * ECH) + k4);
    ushort4 u;
    u.x = f2bf(v.x); u.y = f2bf(v.y); u.z = f2bf(v.z); u.w = f2bf(v.w);
    *(ushort4*)&xsb[e][k4 * 4] = u;
  }

  // ---- zero sweep for this slab's regions (streams while we compute) ----
  {
    float* ob = out + (size_t)e0 * OPE;
    if (slab == 0) {
      zwrite<240>(ob, tid, 80);    // lm0 R1 + lm1 (merged)
      zwrite<144>(ob, tid, 496);   // lm3
      zwrite<144>(ob, tid, 976);   // lm6
      zwrite<144>(ob, tid, 1456);  // lm9
    } else if (slab == 1) {
      zwrite<160>(ob, tid, 320);   // lm2 (invalid)
      zwrite<64>(ob, tid, 656);  zwrite<64>(ob, tid, 736);   // lm4
      zwrite<64>(ob, tid, 1136); zwrite<64>(ob, tid, 1216);  // lm7
      zwrite<64>(ob, tid, 1296); zwrite<64>(ob, tid, 1376);  // lm8
      zwrite<144>(ob, tid, 1936);  // lm12
    } else {
      zwrite<160>(ob, tid, 800);   // lm5 (invalid)
      zwrite<64>(ob, tid, 1616); zwrite<64>(ob, tid, 1696);  // lm10
      zwrite<64>(ob, tid, 1776); zwrite<64>(ob, tid, 1856);  // lm11
      zwrite<64>(ob, tid, 2096); zwrite<64>(ob, tid, 2176);  // lm13
      zwrite<64>(ob, tid, 2256); zwrite<64>(ob, tid, 2336);  // lm14
    }
  }
  __syncthreads();

  // ---- GEMM1: h_pre = xe @ w1 (+b1), wave w owns output cols [32w,32w+32) ----
  {
    const int n0 = wave * 32;
    f32x4 c0 = {0.f, 0.f, 0.f, 0.f}, c1 = {0.f, 0.f, 0.f, 0.f};
#pragma unroll
    for (int ks = 0; ks < 4; ++ks) {
      bf16x8 a  = *(const bf16x8*)&xsb[lr][lq * 8 + ks * 32];
      bf16x8 bA = *(const bf16x8*)(w1t + (size_t)(n0 + lr) * 128 + lq * 8 + ks * 32);
      bf16x8 bB = *(const bf16x8*)(w1t + (size_t)(n0 + 16 + lr) * 128 + lq * 8 + ks * 32);
      c0 = __builtin_amdgcn_mfma_f32_16x16x32_bf16(a, bA, c0, 0, 0, 0);
      c1 = __builtin_amdgcn_mfma_f32_16x16x32_bf16(a, bB, c1, 0, 0, 0);
    }
    float bb0 = b1[n0 + lr], bb1 = b1[n0 + 16 + lr];
#pragma unroll
    for (int i = 0; i < 4; ++i) {
      int e = 4 * lq + i;
      hp[e][n0 + lr]      = c0[i] + bb0;
      hp[e][n0 + 16 + lr] = c1[i] + bb1;
    }
  }
  __syncthreads();

  // ---- LayerNorm + SiLU -> hb (bf16). 16 threads per edge, 8 ch each ----
  {
    int e = tid >> 4, j = tid & 15;
    float v[8];
    float4 a = *((const float4*)&hp[e][j * 8]);
    float4 b = *((const float4*)&hp[e][j * 8 + 4]);
    v[0] = a.x; v[1] = a.y; v[2] = a.z; v[3] = a.w;
    v[4] = b.x; v[5] = b.y; v[6] = b.z; v[7] = b.w;
    float s = 0.f, q = 0.f;
#pragma unroll
    for (int i = 0; i < 8; ++i) { s += v[i]; q += v[i] * v[i]; }
#pragma unroll
    for (int mk = 1; mk <= 8; mk <<= 1) {
      s += __shfl_xor(s, mk, 64);
      q += __shfl_xor(q, mk, 64);
    }
    float mean = s * (1.f / 128.f);
    float var  = q * (1.f / 128.f) - mean * mean;
    float rstd = rsqrtf(var + 1e-5f);
    float4 g0 = *((const float4*)&lng[j * 8]), g1 = *((const float4*)&lng[j * 8 + 4]);
    float4 t0 = *((const float4*)&lnb[j * 8]), t1 = *((const float4*)&lnb[j * 8 + 4]);
    float gg[8] = {g0.x, g0.y, g0.z, g0.w, g1.x, g1.y, g1.z, g1.w};
    float bb[8] = {t0.x, t0.y, t0.z, t0.w, t1.x, t1.y, t1.z, t1.w};
    ushort4 o0, o1;
    unsigned short uo[8];
#pragma unroll
    for (int i = 0; i < 8; ++i) {
      float hn = (v[i] - mean) * rstd * gg[i] + bb[i];
      float sv = hn / (1.f + __expf(-hn));
      uo[i] = f2bf(sv);
    }
    o0.x = uo[0]; o0.y = uo[1]; o0.z = uo[2]; o0.w = uo[3];
    o1.x = uo[4]; o1.y = uo[5]; o1.z = uo[6]; o1.w = uo[7];
    *(ushort4*)&hb[e][j * 8]     = o0;
    *(ushort4*)&hb[e][j * 8 + 4] = o1;
  }
  __syncthreads();

  // hoist A-fragments of h (same for every (l,m))
  bf16x8 hfr[4];
#pragma unroll
  for (int ks = 0; ks < 4; ++ks) hfr[ks] = *(const bf16x8*)&hb[lr][lq * 8 + ks * 32];

  // slab -> 4 valid lm values (einsum-cost balanced: 256/240/256 MFMA)
  static const signed char lmtab[3][4] = {{0, 3, 6, 9}, {12, 4, 7, 8}, {10, 11, 13, 14}};

#pragma unroll 1
  for (int vi = 0; vi < 4; ++vi) {
    const int lm = lmtab[slab][vi];
    const int m = lm % 3;

    const int n0 = wave * 32;

    // ---- prefetch x for this lm into registers (hides HBM latency under MFMAs)
    float xv0[4], xv1[4];
#pragma unroll
    for (int i = 0; i < 4; ++i) {
      const float* xrow = x + (size_t)(e0 + 4 * lq + i) * RAD + lm * 128;
      xv0[i] = xrow[n0 + lr];
      xv1[i] = xrow[n0 + 16 + lr];
    }
    float bb0 = b2[lm * 128 + n0 + lr], bb1 = b2[lm * 128 + n0 + 16 + lr];

    // ---- GEMM2 chunk: rad[e, rc] for rc in [32w, 32w+32) ----
    f32x4 r0 = {0.f, 0.f, 0.f, 0.f}, r1 = {0.f, 0.f, 0.f, 0.f};
    const unsigned short* w2base = w2t + (size_t)(lm * 128) * 128;
#pragma unroll
    for (int ks = 0; ks < 4; ++ks) {
      bf16x8 b0 = *(const bf16x8*)(w2base + (size_t)(n0 + lr) * 128 + lq * 8 + ks * 32);
      bf16x8 b1v = *(const bf16x8*)(w2base + (size_t)(n0 + 16 + lr) * 128 + lq * 8 + ks * 32);
      r0 = __builtin_amdgcn_mfma_f32_16x16x32_bf16(hfr[ks], b0, r0, 0, 0, 0);
      r1 = __builtin_amdgcn_mfma_f32_16x16x32_bf16(hfr[ks], b1v, r1, 0, 0, 0);
    }
    // ---- xs = (rad + b2) * x  -> bf16 LDS ----
#pragma unroll
    for (int i = 0; i < 4; ++i) {
      int e = 4 * lq + i;
      xsb[e][n0 + lr]      = f2bf((r0[i] + bb0) * xv0[i]);
      xsb[e][n0 + 16 + lr] = f2bf((r1[i] + bb1) * xv1[i]);
    }
    __syncthreads();

    // ---- einsum: out[e, R, o] = xs @ wt[m][R], masked N ----
    bf16x8 afr[4];
#pragma unroll
    for (int ks = 0; ks < 4; ++ks) afr[ks] = *(const bf16x8*)&xsb[lr][lq * 8 + ks * 32];

    const int totT = (lm == 0) ? 20 : ((m == 0) ? 4 : 8);
    for (int t = wave; t < totT; t += 4) {
      int R, o0v;
      if (lm == 0) { R = 0; o0v = t * 16; }
      else         { R = t >> 2; o0v = (t & 3) * 16; }
      const unsigned short* wb = wt + ((size_t)((m * 2 + R) * 320) + o0v) * 128;
      f32x4 acc = {0.f, 0.f, 0.f, 0.f};
#pragma unroll
      for (int ks = 0; ks < 4; ++ks) {
        bf16x8 b = *(const bf16x8*)(wb + (size_t)lr * 128 + lq * 8 + ks * 32);
        acc = __builtin_amdgcn_mfma_f32_16x16x32_bf16(afr[ks], b, acc, 0, 0, 0);
      }
      float* ob = out + (size_t)(e0 + 4 * lq) * OPE + lm * 640 + R * 320 + o0v + lr;
      ob[0 * OPE] = acc[0];
      ob[1 * OPE] = acc[1];
      ob[2 * OPE] = acc[2];
      ob[3 * OPE] = acc[3];
    }
    __syncthreads();
  }
}

extern "C" void kernel_launch(void* const* d_in, const int* in_sizes, int n_in,
                              void* d_out, int out_size, void* d_ws, size_t ws_size,
                              hipStream_t stream) {
  const float* x   = (const float*)d_in[0];
  const float* xe  = (const float*)d_in[1];
  const float* Wr  = (const float*)d_in[2];
  const float* Wi  = (const float*)d_in[3];
  const float* w1  = (const float*)d_in[4];
  const float* b1  = (const float*)d_in[5];
  const float* lng = (const float*)d_in[6];
  const float* lnb = (const float*)d_in[7];
  const float* w2  = (const float*)d_in[8];
  const float* b2  = (const float*)d_in[9];
  float* out = (float*)d_out;
  unsigned short* ws = (unsigned short*)d_ws;

  const int prepN = 16384 + 245760 + 61440;  // 323584 -> 1264 blocks exactly
  prep_kernel<<<(prepN + 255) / 256, 256, 0, stream>>>(w1, w2, Wr, Wi, ws);
  fused_kernel<<<(NEDGE / BE) * 3, 256, 0, stream>>>(x, xe, b1, lng, lnb, b2, ws, out);
}

// Round 4
// 183.711 us; speedup vs baseline: 1.4424x; 1.4386x over previous
//
#include <hip/hip_runtime.h>

#define NEDGE 20000
#define ECH   128
#define RAD   1920
#define OPE   9600   // output floats per edge (5*3*2*320)
#define BE    16     // edges per block

typedef short bf16x8 __attribute__((ext_vector_type(8)));
typedef float f32x4  __attribute__((ext_vector_type(4)));

__device__ __forceinline__ unsigned short f2bf(float f) {
  unsigned u = __float_as_uint(f);
  u += 0x7fffu + ((u >> 16) & 1u);
  return (unsigned short)(u >> 16);
}

// ---------------- prep: transposed bf16 weights into ws ----------------
// ws layout (ushort):
//   [0,16384)                w1t[128 n][128 k]  = w1[k][n]
//   [16384, 16384+245760)    w2t[1920 n][128 k] = w2[k][n]
//   [262144, 262144+245760)  wt[m][R][320 o][128 rc] combined complex weight
__global__ __launch_bounds__(256) void prep_kernel(
    const float* __restrict__ w1, const float* __restrict__ w2,
    const float* __restrict__ Wr, const float* __restrict__ Wi,
    unsigned short* __restrict__ ws) {
  int gid = blockIdx.x * 256 + threadIdx.x;
  unsigned short* w1t = ws;
  unsigned short* w2t = ws + 16384;
  unsigned short* wt  = ws + 16384 + 245760;
  if (gid < 16384) {
    int k = gid >> 7, n = gid & 127;
    w1t[n * 128 + k] = f2bf(w1[gid]);
  } else if (gid < 16384 + 245760) {
    int i = gid - 16384;
    int k = i / 1920, n = i - k * 1920;
    w2t[n * 128 + k] = f2bf(w2[i]);
  } else if (gid < 16384 + 245760 + 61440) {
    int i = gid - (16384 + 245760);      // i = (m*64+c)*320 + o
    int o = i % 320, mc = i / 320;
    int c = mc & 63, m = mc >> 6;
    float vr = Wr[i], vi = Wi[i];
    size_t b0 = ((size_t)((m * 2 + 0) * 320 + o)) * 128;
    size_t b1 = ((size_t)((m * 2 + 1) * 320 + o)) * 128;
    wt[b0 + c]      = f2bf(vr);    // R=0, r=0:  W_r
    wt[b0 + 64 + c] = f2bf(-vi);   // R=0, r=1: -W_i
    wt[b1 + c]      = f2bf(vi);    // R=1, r=0:  W_i
    wt[b1 + 64 + c] = f2bf(vr);    // R=1, r=1:  W_r
  }
}

// balanced zero writer: N4 is a compile-time divisor; nontemporal stores
template<int N4>
__device__ __forceinline__ void zwrite(float* __restrict__ outb, int tid, int s4) {
  const f32x4 z4 = {0.f, 0.f, 0.f, 0.f};
  for (int p = tid; p < N4 * BE; p += 256) {
    int e = p / N4, f = p - e * N4;
    __builtin_nontemporal_store(z4, (f32x4*)(outb + (size_t)e * OPE) + (s4 + f));
  }
}

// ---------------- fused: MLP + modulation + SO2 einsum + masked write ----
// grid.x = 3750: eb = bid/3 owns edges [eb*16, eb*16+16); slab = bid%3 owns
// 4 of the 12 valid (l,m) plus a share of the zero regions.
__global__ __launch_bounds__(256, 4) void fused_kernel(
    const float* __restrict__ x,  const float* __restrict__ xe,
    const float* __restrict__ b1, const float* __restrict__ lng,
    const float* __restrict__ lnb, const float* __restrict__ b2,
    const unsigned short* __restrict__ ws, float* __restrict__ out) {

  const unsigned short* w1t = ws;
  const unsigned short* w2t = ws + 16384;
  const unsigned short* wt  = ws + 16384 + 245760;

  __shared__ unsigned short xsb[BE][136];  // xe tile (bf16), then xs tiles
  __shared__ unsigned short hb[BE][136];   // h after LN+SiLU (bf16)
  __shared__ float hp[BE][132];            // pre-LN h (fp32)

  const int tid  = threadIdx.x;
  const int wave = tid >> 6, lane = tid & 63;
  const int lq = lane >> 4, lr = lane & 15;
  const int eb = blockIdx.x / 3, slab = blockIdx.x % 3;
  const int e0 = eb * BE;

  // ---- load x_edge tile as bf16 into LDS ----
  for (int s = tid; s < BE * 32; s += 256) {
    int e = s >> 5, k4 = s & 31;
    float4 v = *((const float4*)(xe + (size_t)(e0 + e) * ECH) + k4);
    ushort4 u;
    u.x = f2bf(v.x); u.y = f2bf(v.y); u.z = f2bf(v.z); u.w = f2bf(v.w);
    *(ushort4*)&xsb[e][k4 * 4] = u;
  }

  // ---- zero sweep for this slab's regions (streams while we compute) ----
  {
    float* ob = out + (size_t)e0 * OPE;
    if (slab == 0) {
      zwrite<240>(ob, tid, 80);    // lm0 R1 + lm1 (merged)
      zwrite<144>(ob, tid, 496);   // lm3
      zwrite<144>(ob, tid, 976);   // lm6
      zwrite<144>(ob, tid, 1456);  // lm9
    } else if (slab == 1) {
      zwrite<160>(ob, tid, 320);   // lm2 (invalid)
      zwrite<64>(ob, tid, 656);  zwrite<64>(ob, tid, 736);   // lm4
      zwrite<64>(ob, tid, 1136); zwrite<64>(ob, tid, 1216);  // lm7
      zwrite<64>(ob, tid, 1296); zwrite<64>(ob, tid, 1376);  // lm8
      zwrite<144>(ob, tid, 1936);  // lm12
    } else {
      zwrite<160>(ob, tid, 800);   // lm5 (invalid)
      zwrite<64>(ob, tid, 1616); zwrite<64>(ob, tid, 1696);  // lm10
      zwrite<64>(ob, tid, 1776); zwrite<64>(ob, tid, 1856);  // lm11
      zwrite<64>(ob, tid, 2096); zwrite<64>(ob, tid, 2176);  // lm13
      zwrite<64>(ob, tid, 2256); zwrite<64>(ob, tid, 2336);  // lm14
    }
  }
  __syncthreads();

  // ---- GEMM1: h_pre = xe @ w1 (+b1), wave w owns output cols [32w,32w+32) ----
  {
    const int n0 = wave * 32;
    f32x4 c0 = {0.f, 0.f, 0.f, 0.f}, c1 = {0.f, 0.f, 0.f, 0.f};
#pragma unroll
    for (int ks = 0; ks < 4; ++ks) {
      bf16x8 a  = *(const bf16x8*)&xsb[lr][lq * 8 + ks * 32];
      bf16x8 bA = *(const bf16x8*)(w1t + (size_t)(n0 + lr) * 128 + lq * 8 + ks * 32);
      bf16x8 bB = *(const bf16x8*)(w1t + (size_t)(n0 + 16 + lr) * 128 + lq * 8 + ks * 32);
      c0 = __builtin_amdgcn_mfma_f32_16x16x32_bf16(a, bA, c0, 0, 0, 0);
      c1 = __builtin_amdgcn_mfma_f32_16x16x32_bf16(a, bB, c1, 0, 0, 0);
    }
    float bb0 = b1[n0 + lr], bb1 = b1[n0 + 16 + lr];
#pragma unroll
    for (int i = 0; i < 4; ++i) {
      int e = 4 * lq + i;
      hp[e][n0 + lr]      = c0[i] + bb0;
      hp[e][n0 + 16 + lr] = c1[i] + bb1;
    }
  }
  __syncthreads();

  // ---- LayerNorm + SiLU -> hb (bf16). 16 threads per edge, 8 ch each ----
  {
    int e = tid >> 4, j = tid & 15;
    float v[8];
    float4 a = *((const float4*)&hp[e][j * 8]);
    float4 b = *((const float4*)&hp[e][j * 8 + 4]);
    v[0] = a.x; v[1] = a.y; v[2] = a.z; v[3] = a.w;
    v[4] = b.x; v[5] = b.y; v[6] = b.z; v[7] = b.w;
    float s = 0.f, q = 0.f;
#pragma unroll
    for (int i = 0; i < 8; ++i) { s += v[i]; q += v[i] * v[i]; }
#pragma unroll
    for (int mk = 1; mk <= 8; mk <<= 1) {
      s += __shfl_xor(s, mk, 64);
      q += __shfl_xor(q, mk, 64);
    }
    float mean = s * (1.f / 128.f);
    float var  = q * (1.f / 128.f) - mean * mean;
    float rstd = rsqrtf(var + 1e-5f);
    float4 g0 = *((const float4*)&lng[j * 8]), g1 = *((const float4*)&lng[j * 8 + 4]);
    float4 t0 = *((const float4*)&lnb[j * 8]), t1 = *((const float4*)&lnb[j * 8 + 4]);
    float gg[8] = {g0.x, g0.y, g0.z, g0.w, g1.x, g1.y, g1.z, g1.w};
    float bb[8] = {t0.x, t0.y, t0.z, t0.w, t1.x, t1.y, t1.z, t1.w};
    ushort4 o0, o1;
    unsigned short uo[8];
#pragma unroll
    for (int i = 0; i < 8; ++i) {
      float hn = (v[i] - mean) * rstd * gg[i] + bb[i];
      float sv = hn / (1.f + __expf(-hn));
      uo[i] = f2bf(sv);
    }
    o0.x = uo[0]; o0.y = uo[1]; o0.z = uo[2]; o0.w = uo[3];
    o1.x = uo[4]; o1.y = uo[5]; o1.z = uo[6]; o1.w = uo[7];
    *(ushort4*)&hb[e][j * 8]     = o0;
    *(ushort4*)&hb[e][j * 8 + 4] = o1;
  }
  __syncthreads();

  // hoist A-fragments of h (same for every (l,m))
  bf16x8 hfr[4];
#pragma unroll
  for (int ks = 0; ks < 4; ++ks) hfr[ks] = *(const bf16x8*)&hb[lr][lq * 8 + ks * 32];

  // slab -> 4 valid lm values (einsum-cost balanced: 256/240/256 MFMA)
  static const signed char lmtab[3][4] = {{0, 3, 6, 9}, {12, 4, 7, 8}, {10, 11, 13, 14}};

#pragma unroll 1
  for (int vi = 0; vi < 4; ++vi) {
    const int lm = lmtab[slab][vi];
    const int m = lm % 3;

    const int n0 = wave * 32;

    // ---- prefetch x for this lm into registers (hides HBM latency under MFMAs)
    float xv0[4], xv1[4];
#pragma unroll
    for (int i = 0; i < 4; ++i) {
      const float* xrow = x + (size_t)(e0 + 4 * lq + i) * RAD + lm * 128;
      xv0[i] = xrow[n0 + lr];
      xv1[i] = xrow[n0 + 16 + lr];
    }
    float bb0 = b2[lm * 128 + n0 + lr], bb1 = b2[lm * 128 + n0 + 16 + lr];

    // ---- GEMM2 chunk: rad[e, rc] for rc in [32w, 32w+32) ----
    f32x4 r0 = {0.f, 0.f, 0.f, 0.f}, r1 = {0.f, 0.f, 0.f, 0.f};
    const unsigned short* w2base = w2t + (size_t)(lm * 128) * 128;
#pragma unroll
    for (int ks = 0; ks < 4; ++ks) {
      bf16x8 b0 = *(const bf16x8*)(w2base + (size_t)(n0 + lr) * 128 + lq * 8 + ks * 32);
      bf16x8 b1v = *(const bf16x8*)(w2base + (size_t)(n0 + 16 + lr) * 128 + lq * 8 + ks * 32);
      r0 = __builtin_amdgcn_mfma_f32_16x16x32_bf16(hfr[ks], b0, r0, 0, 0, 0);
      r1 = __builtin_amdgcn_mfma_f32_16x16x32_bf16(hfr[ks], b1v, r1, 0, 0, 0);
    }
    // ---- xs = (rad + b2) * x  -> bf16 LDS ----
#pragma unroll
    for (int i = 0; i < 4; ++i) {
      int e = 4 * lq + i;
      xsb[e][n0 + lr]      = f2bf((r0[i] + bb0) * xv0[i]);
      xsb[e][n0 + 16 + lr] = f2bf((r1[i] + bb1) * xv1[i]);
    }
    __syncthreads();

    // ---- einsum: out[e, R, o] = xs @ wt[m][R], masked N ----
    bf16x8 afr[4];
#pragma unroll
    for (int ks = 0; ks < 4; ++ks) afr[ks] = *(const bf16x8*)&xsb[lr][lq * 8 + ks * 32];

    const int totT = (lm == 0) ? 20 : ((m == 0) ? 4 : 8);
    for (int t = wave; t < totT; t += 4) {
      int R, o0v;
      if (lm == 0) { R = 0; o0v = t * 16; }
      else         { R = t >> 2; o0v = (t & 3) * 16; }
      const unsigned short* wb = wt + ((size_t)((m * 2 + R) * 320) + o0v) * 128;
      f32x4 acc = {0.f, 0.f, 0.f, 0.f};
#pragma unroll
      for (int ks = 0; ks < 4; ++ks) {
        bf16x8 b = *(const bf16x8*)(wb + (size_t)lr * 128 + lq * 8 + ks * 32);
        acc = __builtin_amdgcn_mfma_f32_16x16x32_bf16(afr[ks], b, acc, 0, 0, 0);
      }
      float* ob = out + (size_t)(e0 + 4 * lq) * OPE + lm * 640 + R * 320 + o0v + lr;
      __builtin_nontemporal_store(acc[0], ob + 0 * OPE);
      __builtin_nontemporal_store(acc[1], ob + 1 * OPE);
      __builtin_nontemporal_store(acc[2], ob + 2 * OPE);
      __builtin_nontemporal_store(acc[3], ob + 3 * OPE);
    }
    __syncthreads();
  }
}

extern "C" void kernel_launch(void* const* d_in, const int* in_sizes, int n_in,
                              void* d_out, int out_size, void* d_ws, size_t ws_size,
                              hipStream_t stream) {
  const float* x   = (const float*)d_in[0];
  const float* xe  = (const float*)d_in[1];
  const float* Wr  = (const float*)d_in[2];
  const float* Wi  = (const float*)d_in[3];
  const float* w1  = (const float*)d_in[4];
  const float* b1  = (const float*)d_in[5];
  const float* lng = (const float*)d_in[6];
  const float* lnb = (const float*)d_in[7];
  const float* w2  = (const float*)d_in[8];
  const float* b2  = (const float*)d_in[9];
  float* out = (float*)d_out;
  unsigned short* ws = (unsigned short*)d_ws;

  const int prepN = 16384 + 245760 + 61440;  // 323584 -> 1264 blocks exactly
  prep_kernel<<<(prepN + 255) / 256, 256, 0, stream>>>(w1, w2, Wr, Wi, ws);
  fused_kernel<<<(NEDGE / BE) * 3, 256, 0, stream>>>(x, xe, b1, lng, lnb, b2, ws, out);
}